// Round 8
// baseline (312.858 us; speedup 1.0000x reference)
//
#include <hip/hip_runtime.h>
#include <hip/hip_bf16.h>

#define NHEAD 4
#define DIN 128
#define DOUT 128

typedef __attribute__((ext_vector_type(8))) short bf16x8;
typedef __attribute__((ext_vector_type(4))) float f32x4;

__device__ __forceinline__ short bfb(float f) {
    __hip_bfloat16 h = __float2bfloat16(f);
    return *reinterpret_cast<short*>(&h);
}
__device__ __forceinline__ float bf2f(unsigned short u) {
    return __uint_as_float(((unsigned int)u) << 16);
}
__device__ __forceinline__ float2 bfpair(unsigned int u) {
    float2 r;
    r.x = __uint_as_float(u << 16);
    r.y = __uint_as_float(u & 0xFFFF0000u);
    return r;
}
__device__ __forceinline__ unsigned int pk2(float lo, float hi) {
    return (unsigned int)(unsigned short)bfb(lo) |
           ((unsigned int)(unsigned short)bfb(hi) << 16);
}
__device__ __forceinline__ bf16x8 cvt8(const float* __restrict__ p) {
    float4 u = *(const float4*)p;
    float4 v = *(const float4*)(p + 4);
    bf16x8 r;
    r[0] = bfb(u.x); r[1] = bfb(u.y); r[2] = bfb(u.z); r[3] = bfb(u.w);
    r[4] = bfb(v.x); r[5] = bfb(v.y); r[6] = bfb(v.z); r[7] = bfb(v.w);
    return r;
}

// ---------------- KP: W->bf16 conversion + CSR rowptr (fused prep) ----------------
__global__ __launch_bounds__(256) void kprep(
    const float* __restrict__ W0, const float* __restrict__ W1,
    const int* __restrict__ erow, uint4* __restrict__ Wbf,
    int* __restrict__ rowptr, int n, int E)
{
    const int i = blockIdx.x * 256 + threadIdx.x;
    const int nW8 = (2 * DOUT * DIN) / 8;     // 4096
    if (i < nW8) {
        const float* s = (i < nW8 / 2) ? (W0 + (size_t)i * 8)
                                       : (W1 + (size_t)(i - nW8 / 2) * 8);
        float4 a = ((const float4*)s)[0];
        float4 b = ((const float4*)s)[1];
        Wbf[i] = make_uint4(pk2(a.x, a.y), pk2(a.z, a.w),
                            pk2(b.x, b.y), pk2(b.z, b.w));
    } else {
        int nn = i - nW8;
        if (nn <= n) {
            int lo = 0, hi = E;
            while (lo < hi) { int mid = (lo + hi) >> 1; if (erow[mid] < nn) lo = mid + 1; else hi = mid; }
            rowptr[nn] = lo;
        }
    }
}

// ---------------- K1: fused f32->bf16 staging + MFMA dual projection ----------------
// 512 threads = 8 waves; wave w owns 32 channels (one head): w<4 -> self half
// (emits 0.5*layernorm(h_self) bf16, node-major + att_self), w>=4 -> h_neigh
// (PLANE-major: plane p = channel/16, 3.2MB per plane) + att_neigh.
// Feat tile (64 nodes) read as f32, converted, staged in LDS (XOR-swizzled).
#define NPB 64

__global__ __launch_bounds__(512) void k1_mfma(
    const float* __restrict__ feat,        // [n][128] f32
    const uint4* __restrict__ Wbf,         // [256][16]
    const float* __restrict__ b0, const float* __restrict__ b1,
    const float* __restrict__ att, const float* __restrict__ scale,
    const float* __restrict__ offset,
    unsigned short* __restrict__ nsbuf, unsigned short* __restrict__ hpl,
    float* __restrict__ att_self, float* __restrict__ att_neigh, int n)
{
    __shared__ uint4 lds[NPB * 16];        // 16 KB
    const int t = threadIdx.x;
    const int w = t >> 6;
    const int lane = t & 63;
    const int col = lane & 15;
    const int rg = lane >> 4;
    const bool selfhalf = (w < 4);
    const int hd = w & 3;
    const size_t pstride = (size_t)n * 16;

    bf16x8 afr[2][4];
    #pragma unroll
    for (int ct = 0; ct < 2; ct++) {
        const uint4* wr = Wbf + (size_t)(w * 32 + ct * 16 + col) * 16;
        #pragma unroll
        for (int kk = 0; kk < 4; kk++) {
            uint4 u = wr[kk * 4 + rg];
            *(uint4*)&afr[ct][kk] = u;
        }
    }
    float4 bias4[2], att4[2], sc4[2], of4[2];
    #pragma unroll
    for (int ct = 0; ct < 2; ct++) {
        int chg = w * 32 + ct * 16 + rg * 4;
        int chm = chg & 127;
        bias4[ct] = *(const float4*)((selfhalf ? b0 : b1) + chm);
        att4[ct]  = *(const float4*)(att + chg);
        sc4[ct]   = *(const float4*)(scale + 128 + chm);
        of4[ct]   = *(const float4*)(offset + 128 + chm);
    }

    const int base_node = blockIdx.x * NPB;
    // stage + convert: lds[nl*16+sl] = bf16 of feat[ng][ (sl^(nl&7))*8 .. +8 )
    #pragma unroll
    for (int j = 0; j < 2; j++) {
        int li = j * 512 + t;
        int nl = li >> 4;
        int sl = li & 15;
        int ng = base_node + nl;
        if (ng >= n) ng = n - 1;
        bf16x8 v = cvt8(feat + (size_t)ng * DIN + (sl ^ (nl & 7)) * 8);
        lds[li] = *(uint4*)&v;
    }
    __syncthreads();

    const int ntiles = (n + 15) >> 4;
    const int tile0 = blockIdx.x * (NPB / 16);
    const int tile1 = min(tile0 + NPB / 16, ntiles);

    for (int tile = tile0; tile < tile1; tile++) {
        const int tt = tile - tile0;
        const int nl = tt * 16 + col;
        bf16x8 bfr[4];
        #pragma unroll
        for (int kk = 0; kk < 4; kk++) {
            uint4 u = lds[nl * 16 + ((kk * 4 + rg) ^ (col & 7))];
            *(uint4*)&bfr[kk] = u;
        }

        f32x4 acc[2] = {{0.f,0.f,0.f,0.f},{0.f,0.f,0.f,0.f}};
        #pragma unroll
        for (int kk = 0; kk < 4; kk++) {
            acc[0] = __builtin_amdgcn_mfma_f32_16x16x32_bf16(afr[0][kk], bfr[kk], acc[0], 0, 0, 0);
            acc[1] = __builtin_amdgcn_mfma_f32_16x16x32_bf16(afr[1][kk], bfr[kk], acc[1], 0, 0, 0);
        }

        const int node = tile * 16 + col;
        const bool valid = node < n;

        float v[2][4];
        float p = 0.f;
        #pragma unroll
        for (int ct = 0; ct < 2; ct++) {
            v[ct][0] = fmaxf(acc[ct][0] + bias4[ct].x, 0.f);
            v[ct][1] = fmaxf(acc[ct][1] + bias4[ct].y, 0.f);
            v[ct][2] = fmaxf(acc[ct][2] + bias4[ct].z, 0.f);
            v[ct][3] = fmaxf(acc[ct][3] + bias4[ct].w, 0.f);
            p += v[ct][0] * att4[ct].x + v[ct][1] * att4[ct].y
               + v[ct][2] * att4[ct].z + v[ct][3] * att4[ct].w;
        }
        p += __shfl_xor(p, 16);
        p += __shfl_xor(p, 32);

        if (selfhalf) {
            float s = v[0][0]+v[0][1]+v[0][2]+v[0][3]+v[1][0]+v[1][1]+v[1][2]+v[1][3];
            s += __shfl_xor(s, 16);
            s += __shfl_xor(s, 32);
            float m = s * (1.f / 32.f);
            float q = 0.f;
            #pragma unroll
            for (int ct = 0; ct < 2; ct++)
                #pragma unroll
                for (int j = 0; j < 4; j++) { float d = v[ct][j] - m; q += d * d; }
            q += __shfl_xor(q, 16);
            q += __shfl_xor(q, 32);
            float r = rsqrtf(q * (1.f / 32.f) + 1e-9f);
            #pragma unroll
            for (int ct = 0; ct < 2; ct++) {
                float n0 = 0.5f * ((v[ct][0] - m) * sc4[ct].x * r + of4[ct].x);
                float n1 = 0.5f * ((v[ct][1] - m) * sc4[ct].y * r + of4[ct].y);
                float n2 = 0.5f * ((v[ct][2] - m) * sc4[ct].z * r + of4[ct].z);
                float n3 = 0.5f * ((v[ct][3] - m) * sc4[ct].w * r + of4[ct].w);
                ushort4 st;
                st.x = (unsigned short)bfb(n0); st.y = (unsigned short)bfb(n1);
                st.z = (unsigned short)bfb(n2); st.w = (unsigned short)bfb(n3);
                if (valid)
                    *(ushort4*)(nsbuf + (size_t)node * DOUT + hd * 32 + ct * 16 + rg * 4) = st;
            }
            if (rg == 0 && valid)
                att_self[(size_t)node * NHEAD + hd] = p > 0.f ? p : 0.2f * p;
        } else {
            #pragma unroll
            for (int ct = 0; ct < 2; ct++) {
                ushort4 st;
                st.x = (unsigned short)bfb(v[ct][0]); st.y = (unsigned short)bfb(v[ct][1]);
                st.z = (unsigned short)bfb(v[ct][2]); st.w = (unsigned short)bfb(v[ct][3]);
                int plane = hd * 2 + ct;
                if (valid)
                    *(ushort4*)(hpl + (size_t)plane * pstride + (size_t)node * 16 + rg * 4) = st;
            }
            if (rg == 0 && valid)
                att_neigh[(size_t)node * NHEAD + hd] = p > 0.f ? p : 0.2f * p;
        }
    }
}

// ---------------- K3a: XCD-sliced weighted aggregation ----------------
// Block b: slice = b&7 (one 16-channel plane, 3.2MB -> L2-resident on its XCD),
// chunk = b>>3 -> 32 nodes (4 waves x 8 nodes). Wave processes one node at a
// time, 8 edges in parallel (8 groups of 8 lanes; lane owns 2 channels).
__global__ __launch_bounds__(256) void k3a_slice(
    const int* __restrict__ rowptr, const int* __restrict__ ecol,
    const float* __restrict__ eval,
    const float* __restrict__ att_self, const float* __restrict__ att_neigh,
    const unsigned short* __restrict__ hpl, unsigned short* __restrict__ aggpl,
    int n)
{
    const int t = threadIdx.x;
    const int wv = t >> 6, lane = t & 63;
    const int grp = lane >> 3, gl = lane & 7;
    const int b = blockIdx.x;
    const int slice = b & 7, chunk = b >> 3;
    const int head = slice >> 1;
    const size_t pstride = (size_t)n * 16;
    const unsigned short* plane = hpl + (size_t)slice * pstride;
    unsigned short* aplane = aggpl + (size_t)slice * pstride;

    const int node0 = chunk * 32 + wv * 8;
    for (int ni = 0; ni < 8; ni++) {
        const int nid = node0 + ni;
        if (nid >= n) return;
        const int start = rowptr[nid], end = rowptr[nid + 1];
        const float as = att_self[(size_t)nid * NHEAD + head];
        float ax = 0.f, ay = 0.f, sumw = 0.f;
        for (int e = start; e < end; e += 8) {
            int ee = e + grp;
            bool vd = ee < end;
            int col = vd ? ecol[ee] : 0;
            float ev = vd ? eval[ee] : 0.f;
            float an = att_neigh[(size_t)col * NHEAD + head];
            unsigned int hv = *(const unsigned int*)(plane + (size_t)col * 16 + gl * 2);
            float wh = __expf(as + an) * ev;
            sumw += wh;
            float2 p = bfpair(hv);
            ax = fmaf(wh, p.x, ax);
            ay = fmaf(wh, p.y, ay);
        }
        ax += __shfl_xor(ax, 8);   ax += __shfl_xor(ax, 16);   ax += __shfl_xor(ax, 32);
        ay += __shfl_xor(ay, 8);   ay += __shfl_xor(ay, 16);   ay += __shfl_xor(ay, 32);
        sumw += __shfl_xor(sumw, 8); sumw += __shfl_xor(sumw, 16); sumw += __shfl_xor(sumw, 32);
        if (grp == 0) {
            float rd = 1.f / fmaxf(sumw, 1e-10f);
            *(unsigned int*)(aplane + (size_t)nid * 16 + gl * 2) = pk2(ax * rd, ay * rd);
        }
    }
}

// ---------------- K4: per-head layernorm of agg + combine with nsbuf ----------------
// 256 threads = 16 nodes (16 lanes/node, 8 ch/lane). Pure streaming.
__device__ __forceinline__ float group4_sum(float v) {
    v += __shfl_xor(v, 1);
    v += __shfl_xor(v, 2);
    return v;
}

__global__ __launch_bounds__(256) void k4_combine(
    const unsigned short* __restrict__ aggpl, const unsigned short* __restrict__ nsbuf,
    const float* __restrict__ scale, const float* __restrict__ offset,
    float* __restrict__ out, int n)
{
    const int t = threadIdx.x;
    const int nid = blockIdx.x * 16 + (t >> 4);
    const int lane = t & 15;
    if (nid >= n) return;
    const size_t pstride = (size_t)n * 16;
    const int plane = lane >> 1, off8 = (lane & 1) * 8;
    const int c8 = lane * 8;

    uint4 av = *(const uint4*)(aggpl + (size_t)plane * pstride + (size_t)nid * 16 + off8);
    float a[8];
    { float2 p;
      p = bfpair(av.x); a[0] = p.x; a[1] = p.y;
      p = bfpair(av.y); a[2] = p.x; a[3] = p.y;
      p = bfpair(av.z); a[4] = p.x; a[5] = p.y;
      p = bfpair(av.w); a[6] = p.x; a[7] = p.y; }

    float s0 = 0.f;
    #pragma unroll
    for (int j = 0; j < 8; j++) s0 += a[j];
    float m0 = group4_sum(s0) * (1.f / 32.f);
    float d[8], q0 = 0.f;
    #pragma unroll
    for (int j = 0; j < 8; j++) { d[j] = a[j] - m0; q0 += d[j] * d[j]; }
    float r0 = rsqrtf(group4_sum(q0) * (1.f / 32.f) + 1e-9f);

    float4 sc0a = *(const float4*)(scale + c8);
    float4 sc0b = *(const float4*)(scale + c8 + 4);
    float4 of0a = *(const float4*)(offset + c8);
    float4 of0b = *(const float4*)(offset + c8 + 4);
    const float sc0[8] = {sc0a.x, sc0a.y, sc0a.z, sc0a.w, sc0b.x, sc0b.y, sc0b.z, sc0b.w};
    const float of0[8] = {of0a.x, of0a.y, of0a.z, of0a.w, of0b.x, of0b.y, of0b.z, of0b.w};

    uint4 nv = *(const uint4*)(nsbuf + (size_t)nid * DOUT + c8);
    float ns[8];
    { float2 p;
      p = bfpair(nv.x); ns[0] = p.x; ns[1] = p.y;
      p = bfpair(nv.y); ns[2] = p.x; ns[3] = p.y;
      p = bfpair(nv.z); ns[4] = p.x; ns[5] = p.y;
      p = bfpair(nv.w); ns[6] = p.x; ns[7] = p.y; }

    float o[8];
    #pragma unroll
    for (int j = 0; j < 8; j++)
        o[j] = 0.5f * (d[j] * sc0[j] * r0 + of0[j]) + ns[j];

    float4 oa = make_float4(o[0], o[1], o[2], o[3]);
    float4 ob = make_float4(o[4], o[5], o[6], o[7]);
    *(float4*)(out + (size_t)nid * DOUT + c8)     = oa;
    *(float4*)(out + (size_t)nid * DOUT + c8 + 4) = ob;
}

extern "C" void kernel_launch(void* const* d_in, const int* in_sizes, int n_in,
                              void* d_out, int out_size, void* d_ws, size_t ws_size,
                              hipStream_t stream) {
    const float* feat  = (const float*)d_in[0];
    const int*   erow  = (const int*)  d_in[1];
    const int*   ecol  = (const int*)  d_in[2];
    const float* eval  = (const float*)d_in[3];
    const float* W0    = (const float*)d_in[4];
    const float* b0    = (const float*)d_in[5];
    const float* W1    = (const float*)d_in[6];
    const float* b1    = (const float*)d_in[7];
    const float* att   = (const float*)d_in[8];
    const float* scale = (const float*)d_in[9];
    const float* offs  = (const float*)d_in[10];
    const int n = in_sizes[0] / DIN;
    const int E = in_sizes[2];

    unsigned short* nsbuf = (unsigned short*)d_ws;                   // n*128
    unsigned short* hpl   = nsbuf + (size_t)n * DOUT;                // n*128 (8 planes)
    unsigned short* aggpl = hpl   + (size_t)n * DOUT;                // n*128 (8 planes)
    unsigned short* Wbf   = aggpl + (size_t)n * DOUT;                // 32768
    float* att_self  = (float*)(Wbf + 2 * DOUT * DIN);
    float* att_neigh = att_self  + (size_t)n * NHEAD;
    int*   rowptr    = (int*)(att_neigh + (size_t)n * NHEAD);

    const int nW8 = (2 * DOUT * DIN) / 8;
    kprep<<<(nW8 + n + 1 + 255) / 256, 256, 0, stream>>>(
        W0, W1, erow, (uint4*)Wbf, rowptr, n, E);
    k1_mfma<<<(n + NPB - 1) / NPB, 512, 0, stream>>>(
        feat, (const uint4*)Wbf, b0, b1, att, scale, offs,
        nsbuf, hpl, att_self, att_neigh, n);
    k3a_slice<<<8 * ((n + 31) / 32), 256, 0, stream>>>(
        rowptr, ecol, eval, att_self, att_neigh, hpl, aggpl, n);
    k4_combine<<<(n + 15) / 16, 256, 0, stream>>>(
        aggpl, nsbuf, scale, offs, (float*)d_out, n);
}

// Round 9
// 134.803 us; speedup vs baseline: 2.3209x; 2.3209x over previous
//
#include <hip/hip_runtime.h>
#include <hip/hip_bf16.h>

#define NHEAD 4
#define DIN 128
#define DOUT 128

typedef __attribute__((ext_vector_type(8))) short bf16x8;
typedef __attribute__((ext_vector_type(4))) float f32x4;

__device__ __forceinline__ short bfb(float f) {
    __hip_bfloat16 h = __float2bfloat16(f);
    return *reinterpret_cast<short*>(&h);
}
__device__ __forceinline__ float bf2f(unsigned short u) {
    return __uint_as_float(((unsigned int)u) << 16);
}
__device__ __forceinline__ float2 bfpair(unsigned int u) {
    float2 r;
    r.x = __uint_as_float(u << 16);
    r.y = __uint_as_float(u & 0xFFFF0000u);
    return r;
}
__device__ __forceinline__ bf16x8 cvt8(const float* __restrict__ p) {
    float4 u = *(const float4*)p;
    float4 v = *(const float4*)(p + 4);
    bf16x8 r;
    r[0] = bfb(u.x); r[1] = bfb(u.y); r[2] = bfb(u.z); r[3] = bfb(u.w);
    r[4] = bfb(v.x); r[5] = bfb(v.y); r[6] = bfb(v.z); r[7] = bfb(v.w);
    return r;
}

// ---------------- K2: CSR offsets by binary search on sorted edge_row ----------------
__global__ void k2_rowptr(const int* __restrict__ erow, int* __restrict__ rowptr,
                          int n_nodes, int nedge)
{
    int n = blockIdx.x * blockDim.x + threadIdx.x;
    if (n > n_nodes) return;
    int lo = 0, hi = nedge;
    while (lo < hi) { int mid = (lo + hi) >> 1; if (erow[mid] < n) lo = mid + 1; else hi = mid; }
    rowptr[n] = lo;
}

// ---------------- K1: fused staging + MFMA dual projection + epilogues ----------------
// 512 threads = 8 waves; wave w owns 32 channels (one head): w<4 -> self half
// (emits 0.5*layernorm(h_self) bf16 into nsbuf + att_self), w>=4 -> h_neigh bf16
// node-major + att_neigh. W read as f32 (128KB hot, L2-resident) and cvt'd in regs.
// Feat tile (64 nodes) read f32, cvt'd, staged once in LDS (XOR-swizzled slots).
#define NPB 64

__global__ __launch_bounds__(512) void k1_mfma(
    const float* __restrict__ feat,
    const float* __restrict__ W0, const float* __restrict__ W1,
    const float* __restrict__ b0, const float* __restrict__ b1,
    const float* __restrict__ att, const float* __restrict__ scale,
    const float* __restrict__ offset,
    unsigned short* __restrict__ nsbuf, unsigned short* __restrict__ h_neigh,
    float* __restrict__ att_self, float* __restrict__ att_neigh, int n)
{
    __shared__ uint4 lds[NPB * 16];        // 16 KB
    const int t = threadIdx.x;
    const int w = t >> 6;
    const int lane = t & 63;
    const int col = lane & 15;
    const int rg = lane >> 4;
    const bool selfhalf = (w < 4);
    const int hd = w & 3;

    // A fragments: rows (w*32 + ct*16 + col) of W0|W1, cvt f32->bf16
    bf16x8 afr[2][4];
    #pragma unroll
    for (int ct = 0; ct < 2; ct++) {
        int ch = w * 32 + ct * 16 + col;
        int chm = ch & 127;
        const float* wrow = (selfhalf ? W0 : W1) + (size_t)chm * DIN;
        #pragma unroll
        for (int kk = 0; kk < 4; kk++)
            afr[ct][kk] = cvt8(wrow + kk * 32 + rg * 8);
    }
    float4 bias4[2], att4[2], sc4[2], of4[2];
    #pragma unroll
    for (int ct = 0; ct < 2; ct++) {
        int chg = w * 32 + ct * 16 + rg * 4;
        int chm = chg & 127;
        bias4[ct] = *(const float4*)((selfhalf ? b0 : b1) + chm);
        att4[ct]  = *(const float4*)(att + chg);
        sc4[ct]   = *(const float4*)(scale + 128 + chm);
        of4[ct]   = *(const float4*)(offset + 128 + chm);
    }

    const int base_node = blockIdx.x * NPB;
    #pragma unroll
    for (int j = 0; j < 2; j++) {
        int li = j * 512 + t;
        int nl = li >> 4;
        int sl = li & 15;
        int ng = base_node + nl;
        if (ng >= n) ng = n - 1;
        bf16x8 v = cvt8(feat + (size_t)ng * DIN + (sl ^ (nl & 7)) * 8);
        lds[li] = *(uint4*)&v;
    }
    __syncthreads();

    const int ntiles = (n + 15) >> 4;
    const int tile0 = blockIdx.x * (NPB / 16);
    const int tile1 = min(tile0 + NPB / 16, ntiles);

    for (int tile = tile0; tile < tile1; tile++) {
        const int tt = tile - tile0;
        const int nl = tt * 16 + col;
        bf16x8 bfr[4];
        #pragma unroll
        for (int kk = 0; kk < 4; kk++) {
            uint4 u = lds[nl * 16 + ((kk * 4 + rg) ^ (col & 7))];
            *(uint4*)&bfr[kk] = u;
        }

        f32x4 acc[2] = {{0.f,0.f,0.f,0.f},{0.f,0.f,0.f,0.f}};
        #pragma unroll
        for (int kk = 0; kk < 4; kk++) {
            acc[0] = __builtin_amdgcn_mfma_f32_16x16x32_bf16(afr[0][kk], bfr[kk], acc[0], 0, 0, 0);
            acc[1] = __builtin_amdgcn_mfma_f32_16x16x32_bf16(afr[1][kk], bfr[kk], acc[1], 0, 0, 0);
        }

        const int node = tile * 16 + col;
        const bool valid = node < n;

        float v[2][4];
        float p = 0.f;
        #pragma unroll
        for (int ct = 0; ct < 2; ct++) {
            v[ct][0] = fmaxf(acc[ct][0] + bias4[ct].x, 0.f);
            v[ct][1] = fmaxf(acc[ct][1] + bias4[ct].y, 0.f);
            v[ct][2] = fmaxf(acc[ct][2] + bias4[ct].z, 0.f);
            v[ct][3] = fmaxf(acc[ct][3] + bias4[ct].w, 0.f);
            p += v[ct][0] * att4[ct].x + v[ct][1] * att4[ct].y
               + v[ct][2] * att4[ct].z + v[ct][3] * att4[ct].w;
        }
        p += __shfl_xor(p, 16);
        p += __shfl_xor(p, 32);

        if (selfhalf) {
            float s = v[0][0]+v[0][1]+v[0][2]+v[0][3]+v[1][0]+v[1][1]+v[1][2]+v[1][3];
            s += __shfl_xor(s, 16);
            s += __shfl_xor(s, 32);
            float m = s * (1.f / 32.f);
            float q = 0.f;
            #pragma unroll
            for (int ct = 0; ct < 2; ct++)
                #pragma unroll
                for (int j = 0; j < 4; j++) { float d = v[ct][j] - m; q += d * d; }
            q += __shfl_xor(q, 16);
            q += __shfl_xor(q, 32);
            float r = rsqrtf(q * (1.f / 32.f) + 1e-9f);
            #pragma unroll
            for (int ct = 0; ct < 2; ct++) {
                float n0 = 0.5f * ((v[ct][0] - m) * sc4[ct].x * r + of4[ct].x);
                float n1 = 0.5f * ((v[ct][1] - m) * sc4[ct].y * r + of4[ct].y);
                float n2 = 0.5f * ((v[ct][2] - m) * sc4[ct].z * r + of4[ct].z);
                float n3 = 0.5f * ((v[ct][3] - m) * sc4[ct].w * r + of4[ct].w);
                ushort4 st;
                st.x = (unsigned short)bfb(n0); st.y = (unsigned short)bfb(n1);
                st.z = (unsigned short)bfb(n2); st.w = (unsigned short)bfb(n3);
                if (valid)
                    *(ushort4*)(nsbuf + (size_t)node * DOUT + hd * 32 + ct * 16 + rg * 4) = st;
            }
            if (rg == 0 && valid)
                att_self[(size_t)node * NHEAD + hd] = p > 0.f ? p : 0.2f * p;
        } else {
            #pragma unroll
            for (int ct = 0; ct < 2; ct++) {
                ushort4 st;
                st.x = (unsigned short)bfb(v[ct][0]); st.y = (unsigned short)bfb(v[ct][1]);
                st.z = (unsigned short)bfb(v[ct][2]); st.w = (unsigned short)bfb(v[ct][3]);
                if (valid)
                    *(ushort4*)(h_neigh + (size_t)node * DOUT + hd * 32 + ct * 16 + rg * 4) = st;
            }
            if (rg == 0 && valid)
                att_neigh[(size_t)node * NHEAD + hd] = p > 0.f ? p : 0.2f * p;
        }
    }
}

// ---------------- K3: fused softmax + weighted aggregate + agg LN + combine ----------
// 256 threads = 16 nodes/block, 16 lanes/node, 8 channels/thread (uint4 gather).
// 2-deep pipeline (stage B issued while consuming A), cols one batch further ahead.
__device__ __forceinline__ float group4_sum(float v) {
    v += __shfl_xor(v, 1);
    v += __shfl_xor(v, 2);
    return v;
}

__global__ __launch_bounds__(256) void k3_agg(
    const int* __restrict__ rowptr, const int* __restrict__ ecol,
    const float* __restrict__ eval,
    const float* __restrict__ att_self, const float* __restrict__ att_neigh,
    const unsigned short* __restrict__ nsbuf, const unsigned short* __restrict__ h_neigh,
    const float* __restrict__ scale, const float* __restrict__ offset,
    float* __restrict__ out, int n_nodes)
{
    const int t = threadIdx.x;
    const int g = t >> 4;
    const int lane = t & 15;
    const int nid = blockIdx.x * 16 + g;
    if (nid >= n_nodes) return;
    const int head = lane >> 2;
    const int c8 = lane * 8;

    const int start = rowptr[nid], end = rowptr[nid + 1];
    const float as = att_self[(size_t)nid * NHEAD + head];

    float acc[8];
    #pragma unroll
    for (int j = 0; j < 8; j++) acc[j] = 0.f;
    float sumw = 0.f;

    // prologue: stage A data, stage B cols
    float evA[4], anA[4];
    uint4 hvA[4];
    int cB[4];
    {
        int cA[4];
        #pragma unroll
        for (int i = 0; i < 4; i++) cA[i] = (start + i     < end) ? ecol[start + i]     : 0;
        #pragma unroll
        for (int i = 0; i < 4; i++) cB[i] = (start + 4 + i < end) ? ecol[start + 4 + i] : 0;
        #pragma unroll
        for (int i = 0; i < 4; i++) {
            evA[i] = (start + i < end) ? eval[start + i] : 0.f;
            anA[i] = att_neigh[(size_t)cA[i] * NHEAD + head];
            hvA[i] = *(const uint4*)(h_neigh + (size_t)cA[i] * DOUT + c8);
        }
    }

    for (int e = start; e < end; e += 4) {
        // issue stage B loads (edges e+4..e+7)
        float evB[4], anB[4];
        uint4 hvB[4];
        #pragma unroll
        for (int i = 0; i < 4; i++) {
            evB[i] = (e + 4 + i < end) ? eval[e + 4 + i] : 0.f;
            anB[i] = att_neigh[(size_t)cB[i] * NHEAD + head];
            hvB[i] = *(const uint4*)(h_neigh + (size_t)cB[i] * DOUT + c8);
        }
        int cC[4];
        #pragma unroll
        for (int i = 0; i < 4; i++)
            cC[i] = (e + 8 + i < end) ? ecol[e + 8 + i] : 0;

        // consume stage A
        #pragma unroll
        for (int i = 0; i < 4; i++) {
            float wh = __expf(as + anA[i]) * evA[i];
            sumw += wh;
            float2 p;
            p = bfpair(hvA[i].x); acc[0] = fmaf(wh, p.x, acc[0]); acc[1] = fmaf(wh, p.y, acc[1]);
            p = bfpair(hvA[i].y); acc[2] = fmaf(wh, p.x, acc[2]); acc[3] = fmaf(wh, p.y, acc[3]);
            p = bfpair(hvA[i].z); acc[4] = fmaf(wh, p.x, acc[4]); acc[5] = fmaf(wh, p.y, acc[5]);
            p = bfpair(hvA[i].w); acc[6] = fmaf(wh, p.x, acc[6]); acc[7] = fmaf(wh, p.y, acc[7]);
        }
        // rotate
        #pragma unroll
        for (int i = 0; i < 4; i++) {
            evA[i] = evB[i]; anA[i] = anB[i]; hvA[i] = hvB[i];
            cB[i] = cC[i];
        }
    }

    const float rden = 1.f / fmaxf(sumw, 1e-10f);
    float a[8];
    #pragma unroll
    for (int j = 0; j < 8; j++) a[j] = acc[j] * rden;

    // layernorm of agg over the head's 32 channels (4 lanes x 8)
    float s0 = 0.f;
    #pragma unroll
    for (int j = 0; j < 8; j++) s0 += a[j];
    float m0 = group4_sum(s0) * (1.f / 32.f);
    float d[8], q0 = 0.f;
    #pragma unroll
    for (int j = 0; j < 8; j++) { d[j] = a[j] - m0; q0 += d[j] * d[j]; }
    float r0 = rsqrtf(group4_sum(q0) * (1.f / 32.f) + 1e-9f);

    float4 sc0a = *(const float4*)(scale + c8);
    float4 sc0b = *(const float4*)(scale + c8 + 4);
    float4 of0a = *(const float4*)(offset + c8);
    float4 of0b = *(const float4*)(offset + c8 + 4);
    const float sc0[8] = {sc0a.x, sc0a.y, sc0a.z, sc0a.w, sc0b.x, sc0b.y, sc0b.z, sc0b.w};
    const float of0[8] = {of0a.x, of0a.y, of0a.z, of0a.w, of0b.x, of0b.y, of0b.z, of0b.w};

    uint4 nv = *(const uint4*)(nsbuf + (size_t)nid * DOUT + c8);
    float ns[8];
    { float2 p;
      p = bfpair(nv.x); ns[0] = p.x; ns[1] = p.y;
      p = bfpair(nv.y); ns[2] = p.x; ns[3] = p.y;
      p = bfpair(nv.z); ns[4] = p.x; ns[5] = p.y;
      p = bfpair(nv.w); ns[6] = p.x; ns[7] = p.y; }

    float o[8];
    #pragma unroll
    for (int j = 0; j < 8; j++)
        o[j] = 0.5f * (d[j] * sc0[j] * r0 + of0[j]) + ns[j];

    float4 oa = make_float4(o[0], o[1], o[2], o[3]);
    float4 ob = make_float4(o[4], o[5], o[6], o[7]);
    *(float4*)(out + (size_t)nid * DOUT + c8)     = oa;
    *(float4*)(out + (size_t)nid * DOUT + c8 + 4) = ob;
}

extern "C" void kernel_launch(void* const* d_in, const int* in_sizes, int n_in,
                              void* d_out, int out_size, void* d_ws, size_t ws_size,
                              hipStream_t stream) {
    const float* feat  = (const float*)d_in[0];
    const int*   erow  = (const int*)  d_in[1];
    const int*   ecol  = (const int*)  d_in[2];
    const float* eval  = (const float*)d_in[3];
    const float* W0    = (const float*)d_in[4];
    const float* b0    = (const float*)d_in[5];
    const float* W1    = (const float*)d_in[6];
    const float* b1    = (const float*)d_in[7];
    const float* att   = (const float*)d_in[8];
    const float* scale = (const float*)d_in[9];
    const float* offs  = (const float*)d_in[10];
    const int n = in_sizes[0] / DIN;
    const int E = in_sizes[2];

    unsigned short* nsbuf   = (unsigned short*)d_ws;                 // n*128
    unsigned short* h_neigh = nsbuf + (size_t)n * DOUT;              // n*128
    float* att_self  = (float*)(h_neigh + (size_t)n * DOUT);
    float* att_neigh = att_self  + (size_t)n * NHEAD;
    int*   rowptr    = (int*)(att_neigh + (size_t)n * NHEAD);

    k2_rowptr<<<(n + 1 + 255) / 256, 256, 0, stream>>>(erow, rowptr, n, E);
    k1_mfma<<<(n + NPB - 1) / NPB, 512, 0, stream>>>(
        feat, W0, W1, b0, b1, att, scale, offs,
        nsbuf, h_neigh, att_self, att_neigh, n);
    k3_agg<<<(n + 15) / 16, 256, 0, stream>>>(rowptr, ecol, eval, att_self, att_neigh,
                                              nsbuf, h_neigh, scale, offs,
                                              (float*)d_out, n);
}

// Round 10
// 124.452 us; speedup vs baseline: 2.5139x; 1.0832x over previous
//
#include <hip/hip_runtime.h>
#include <hip/hip_bf16.h>

#define NHEAD 4
#define DIN 128
#define DOUT 128

typedef __attribute__((ext_vector_type(8))) short bf16x8;
typedef __attribute__((ext_vector_type(4))) float f32x4;

__device__ __forceinline__ short bfb(float f) {
    __hip_bfloat16 h = __float2bfloat16(f);
    return *reinterpret_cast<short*>(&h);
}
__device__ __forceinline__ float bf2f(unsigned short u) {
    return __uint_as_float(((unsigned int)u) << 16);
}
__device__ __forceinline__ float2 bfpair(unsigned int u) {
    float2 r;
    r.x = __uint_as_float(u << 16);
    r.y = __uint_as_float(u & 0xFFFF0000u);
    return r;
}
__device__ __forceinline__ unsigned int pk2(float lo, float hi) {
    return (unsigned int)(unsigned short)bfb(lo) |
           ((unsigned int)(unsigned short)bfb(hi) << 16);
}
__device__ __forceinline__ bf16x8 cvt8(const float* __restrict__ p) {
    float4 u = *(const float4*)p;
    float4 v = *(const float4*)(p + 4);
    bf16x8 r;
    r[0] = bfb(u.x); r[1] = bfb(u.y); r[2] = bfb(u.z); r[3] = bfb(u.w);
    r[4] = bfb(v.x); r[5] = bfb(v.y); r[6] = bfb(v.z); r[7] = bfb(v.w);
    return r;
}

// ---------------- KP: W->bf16 conversion + CSR rowptr (fused prep) ----------------
__global__ __launch_bounds__(256) void kprep(
    const float* __restrict__ W0, const float* __restrict__ W1,
    const int* __restrict__ erow, uint4* __restrict__ Wbf,
    int* __restrict__ rowptr, int n, int E)
{
    const int i = blockIdx.x * 256 + threadIdx.x;
    const int nW8 = (2 * DOUT * DIN) / 8;     // 4096
    if (i < nW8) {
        const float* s = (i < nW8 / 2) ? (W0 + (size_t)i * 8)
                                       : (W1 + (size_t)(i - nW8 / 2) * 8);
        float4 a = ((const float4*)s)[0];
        float4 b = ((const float4*)s)[1];
        Wbf[i] = make_uint4(pk2(a.x, a.y), pk2(a.z, a.w),
                            pk2(b.x, b.y), pk2(b.z, b.w));
    } else {
        int nn = i - nW8;
        if (nn <= n) {
            int lo = 0, hi = E;
            while (lo < hi) { int mid = (lo + hi) >> 1; if (erow[mid] < nn) lo = mid + 1; else hi = mid; }
            rowptr[nn] = lo;
        }
    }
}

// ---------------- K1: fused staging + MFMA dual projection + epilogues ----------------
// 512 threads = 8 waves; wave w owns 32 channels (one head): w<4 -> self half
// (emits 0.5*layernorm(h_self) bf16 into nsbuf + att_self), w>=4 -> h_neigh bf16
// + att_neigh. A-frags from precomputed Wbf (bf16, L2-hot). Feat tile (128 nodes)
// read f32 (8 independent float4 loads/thread), cvt'd, staged once in LDS
// (XOR-swizzled 16B slots). 8 tiles/block amortize the prologue.
#define NPB 128

__global__ __launch_bounds__(512) void k1_mfma(
    const float* __restrict__ feat,
    const uint4* __restrict__ Wbf,         // [256][16] bf16x8 slots
    const float* __restrict__ b0, const float* __restrict__ b1,
    const float* __restrict__ att, const float* __restrict__ scale,
    const float* __restrict__ offset,
    unsigned short* __restrict__ nsbuf, unsigned short* __restrict__ h_neigh,
    float* __restrict__ att_self, float* __restrict__ att_neigh, int n)
{
    __shared__ uint4 lds[NPB * 16];        // 32 KB
    const int t = threadIdx.x;
    const int w = t >> 6;
    const int lane = t & 63;
    const int col = lane & 15;
    const int rg = lane >> 4;
    const bool selfhalf = (w < 4);
    const int hd = w & 3;

    // A fragments: rows (w*32 + ct*16 + col) of Wbf
    bf16x8 afr[2][4];
    #pragma unroll
    for (int ct = 0; ct < 2; ct++) {
        const uint4* wr = Wbf + (size_t)(w * 32 + ct * 16 + col) * 16;
        #pragma unroll
        for (int kk = 0; kk < 4; kk++) {
            uint4 u = wr[kk * 4 + rg];
            *(uint4*)&afr[ct][kk] = u;
        }
    }
    float4 bias4[2], att4[2], sc4[2], of4[2];
    #pragma unroll
    for (int ct = 0; ct < 2; ct++) {
        int chg = w * 32 + ct * 16 + rg * 4;
        int chm = chg & 127;
        bias4[ct] = *(const float4*)((selfhalf ? b0 : b1) + chm);
        att4[ct]  = *(const float4*)(att + chg);
        sc4[ct]   = *(const float4*)(scale + 128 + chm);
        of4[ct]   = *(const float4*)(offset + 128 + chm);
    }

    const int base_node = blockIdx.x * NPB;
    // stage 128 node rows, cvt f32->bf16; 8 independent float4 loads per thread
    #pragma unroll
    for (int j = 0; j < 4; j++) {
        int li = j * 512 + t;
        int nl = li >> 4;
        int sl = li & 15;
        int ng = base_node + nl;
        if (ng >= n) ng = n - 1;
        bf16x8 v = cvt8(feat + (size_t)ng * DIN + (sl ^ (nl & 7)) * 8);
        lds[li] = *(uint4*)&v;
    }
    __syncthreads();

    const int ntiles = (n + 15) >> 4;
    const int tile0 = blockIdx.x * (NPB / 16);
    const int tile1 = min(tile0 + NPB / 16, ntiles);

    for (int tile = tile0; tile < tile1; tile++) {
        const int tt = tile - tile0;
        const int nl = tt * 16 + col;
        bf16x8 bfr[4];
        #pragma unroll
        for (int kk = 0; kk < 4; kk++) {
            uint4 u = lds[nl * 16 + ((kk * 4 + rg) ^ (col & 7))];
            *(uint4*)&bfr[kk] = u;
        }

        f32x4 acc[2] = {{0.f,0.f,0.f,0.f},{0.f,0.f,0.f,0.f}};
        #pragma unroll
        for (int kk = 0; kk < 4; kk++) {
            acc[0] = __builtin_amdgcn_mfma_f32_16x16x32_bf16(afr[0][kk], bfr[kk], acc[0], 0, 0, 0);
            acc[1] = __builtin_amdgcn_mfma_f32_16x16x32_bf16(afr[1][kk], bfr[kk], acc[1], 0, 0, 0);
        }

        const int node = tile * 16 + col;
        const bool valid = node < n;

        float v[2][4];
        float p = 0.f;
        #pragma unroll
        for (int ct = 0; ct < 2; ct++) {
            v[ct][0] = fmaxf(acc[ct][0] + bias4[ct].x, 0.f);
            v[ct][1] = fmaxf(acc[ct][1] + bias4[ct].y, 0.f);
            v[ct][2] = fmaxf(acc[ct][2] + bias4[ct].z, 0.f);
            v[ct][3] = fmaxf(acc[ct][3] + bias4[ct].w, 0.f);
            p += v[ct][0] * att4[ct].x + v[ct][1] * att4[ct].y
               + v[ct][2] * att4[ct].z + v[ct][3] * att4[ct].w;
        }
        p += __shfl_xor(p, 16);
        p += __shfl_xor(p, 32);

        if (selfhalf) {
            float s = v[0][0]+v[0][1]+v[0][2]+v[0][3]+v[1][0]+v[1][1]+v[1][2]+v[1][3];
            s += __shfl_xor(s, 16);
            s += __shfl_xor(s, 32);
            float m = s * (1.f / 32.f);
            float q = 0.f;
            #pragma unroll
            for (int ct = 0; ct < 2; ct++)
                #pragma unroll
                for (int j = 0; j < 4; j++) { float d = v[ct][j] - m; q += d * d; }
            q += __shfl_xor(q, 16);
            q += __shfl_xor(q, 32);
            float r = rsqrtf(q * (1.f / 32.f) + 1e-9f);
            #pragma unroll
            for (int ct = 0; ct < 2; ct++) {
                float n0 = 0.5f * ((v[ct][0] - m) * sc4[ct].x * r + of4[ct].x);
                float n1 = 0.5f * ((v[ct][1] - m) * sc4[ct].y * r + of4[ct].y);
                float n2 = 0.5f * ((v[ct][2] - m) * sc4[ct].z * r + of4[ct].z);
                float n3 = 0.5f * ((v[ct][3] - m) * sc4[ct].w * r + of4[ct].w);
                ushort4 st;
                st.x = (unsigned short)bfb(n0); st.y = (unsigned short)bfb(n1);
                st.z = (unsigned short)bfb(n2); st.w = (unsigned short)bfb(n3);
                if (valid)
                    *(ushort4*)(nsbuf + (size_t)node * DOUT + hd * 32 + ct * 16 + rg * 4) = st;
            }
            if (rg == 0 && valid)
                att_self[(size_t)node * NHEAD + hd] = p > 0.f ? p : 0.2f * p;
        } else {
            #pragma unroll
            for (int ct = 0; ct < 2; ct++) {
                ushort4 st;
                st.x = (unsigned short)bfb(v[ct][0]); st.y = (unsigned short)bfb(v[ct][1]);
                st.z = (unsigned short)bfb(v[ct][2]); st.w = (unsigned short)bfb(v[ct][3]);
                if (valid)
                    *(ushort4*)(h_neigh + (size_t)node * DOUT + hd * 32 + ct * 16 + rg * 4) = st;
            }
            if (rg == 0 && valid)
                att_neigh[(size_t)node * NHEAD + hd] = p > 0.f ? p : 0.2f * p;
        }
    }
}

// ---------------- K3: fused softmax + weighted aggregate + agg LN + combine ----------
// 256 threads = 16 nodes/block, 16 lanes/node, 8 channels/thread (uint4 gather).
// 2-deep pipeline (stage B issued while consuming A), cols one batch further ahead.
__device__ __forceinline__ float group4_sum(float v) {
    v += __shfl_xor(v, 1);
    v += __shfl_xor(v, 2);
    return v;
}

__global__ __launch_bounds__(256) void k3_agg(
    const int* __restrict__ rowptr, const int* __restrict__ ecol,
    const float* __restrict__ eval,
    const float* __restrict__ att_self, const float* __restrict__ att_neigh,
    const unsigned short* __restrict__ nsbuf, const unsigned short* __restrict__ h_neigh,
    const float* __restrict__ scale, const float* __restrict__ offset,
    float* __restrict__ out, int n_nodes)
{
    const int t = threadIdx.x;
    const int g = t >> 4;
    const int lane = t & 15;
    const int nid = blockIdx.x * 16 + g;
    if (nid >= n_nodes) return;
    const int head = lane >> 2;
    const int c8 = lane * 8;

    const int start = rowptr[nid], end = rowptr[nid + 1];
    const float as = att_self[(size_t)nid * NHEAD + head];

    float acc[8];
    #pragma unroll
    for (int j = 0; j < 8; j++) acc[j] = 0.f;
    float sumw = 0.f;

    // prologue: stage A data, stage B cols
    float evA[4], anA[4];
    uint4 hvA[4];
    int cB[4];
    {
        int cA[4];
        #pragma unroll
        for (int i = 0; i < 4; i++) cA[i] = (start + i     < end) ? ecol[start + i]     : 0;
        #pragma unroll
        for (int i = 0; i < 4; i++) cB[i] = (start + 4 + i < end) ? ecol[start + 4 + i] : 0;
        #pragma unroll
        for (int i = 0; i < 4; i++) {
            evA[i] = (start + i < end) ? eval[start + i] : 0.f;
            anA[i] = att_neigh[(size_t)cA[i] * NHEAD + head];
            hvA[i] = *(const uint4*)(h_neigh + (size_t)cA[i] * DOUT + c8);
        }
    }

    for (int e = start; e < end; e += 4) {
        // issue stage B loads (edges e+4..e+7)
        float evB[4], anB[4];
        uint4 hvB[4];
        #pragma unroll
        for (int i = 0; i < 4; i++) {
            evB[i] = (e + 4 + i < end) ? eval[e + 4 + i] : 0.f;
            anB[i] = att_neigh[(size_t)cB[i] * NHEAD + head];
            hvB[i] = *(const uint4*)(h_neigh + (size_t)cB[i] * DOUT + c8);
        }
        int cC[4];
        #pragma unroll
        for (int i = 0; i < 4; i++)
            cC[i] = (e + 8 + i < end) ? ecol[e + 8 + i] : 0;

        // consume stage A
        #pragma unroll
        for (int i = 0; i < 4; i++) {
            float wh = __expf(as + anA[i]) * evA[i];
            sumw += wh;
            float2 p;
            p = bfpair(hvA[i].x); acc[0] = fmaf(wh, p.x, acc[0]); acc[1] = fmaf(wh, p.y, acc[1]);
            p = bfpair(hvA[i].y); acc[2] = fmaf(wh, p.x, acc[2]); acc[3] = fmaf(wh, p.y, acc[3]);
            p = bfpair(hvA[i].z); acc[4] = fmaf(wh, p.x, acc[4]); acc[5] = fmaf(wh, p.y, acc[5]);
            p = bfpair(hvA[i].w); acc[6] = fmaf(wh, p.x, acc[6]); acc[7] = fmaf(wh, p.y, acc[7]);
        }
        // rotate
        #pragma unroll
        for (int i = 0; i < 4; i++) {
            evA[i] = evB[i]; anA[i] = anB[i]; hvA[i] = hvB[i];
            cB[i] = cC[i];
        }
    }

    const float rden = 1.f / fmaxf(sumw, 1e-10f);
    float a[8];
    #pragma unroll
    for (int j = 0; j < 8; j++) a[j] = acc[j] * rden;

    // layernorm of agg over the head's 32 channels (4 lanes x 8)
    float s0 = 0.f;
    #pragma unroll
    for (int j = 0; j < 8; j++) s0 += a[j];
    float m0 = group4_sum(s0) * (1.f / 32.f);
    float d[8], q0 = 0.f;
    #pragma unroll
    for (int j = 0; j < 8; j++) { d[j] = a[j] - m0; q0 += d[j] * d[j]; }
    float r0 = rsqrtf(group4_sum(q0) * (1.f / 32.f) + 1e-9f);

    float4 sc0a = *(const float4*)(scale + c8);
    float4 sc0b = *(const float4*)(scale + c8 + 4);
    float4 of0a = *(const float4*)(offset + c8);
    float4 of0b = *(const float4*)(offset + c8 + 4);
    const float sc0[8] = {sc0a.x, sc0a.y, sc0a.z, sc0a.w, sc0b.x, sc0b.y, sc0b.z, sc0b.w};
    const float of0[8] = {of0a.x, of0a.y, of0a.z, of0a.w, of0b.x, of0b.y, of0b.z, of0b.w};

    uint4 nv = *(const uint4*)(nsbuf + (size_t)nid * DOUT + c8);
    float ns[8];
    { float2 p;
      p = bfpair(nv.x); ns[0] = p.x; ns[1] = p.y;
      p = bfpair(nv.y); ns[2] = p.x; ns[3] = p.y;
      p = bfpair(nv.z); ns[4] = p.x; ns[5] = p.y;
      p = bfpair(nv.w); ns[6] = p.x; ns[7] = p.y; }

    float o[8];
    #pragma unroll
    for (int j = 0; j < 8; j++)
        o[j] = 0.5f * (d[j] * sc0[j] * r0 + of0[j]) + ns[j];

    float4 oa = make_float4(o[0], o[1], o[2], o[3]);
    float4 ob = make_float4(o[4], o[5], o[6], o[7]);
    *(float4*)(out + (size_t)nid * DOUT + c8)     = oa;
    *(float4*)(out + (size_t)nid * DOUT + c8 + 4) = ob;
}

extern "C" void kernel_launch(void* const* d_in, const int* in_sizes, int n_in,
                              void* d_out, int out_size, void* d_ws, size_t ws_size,
                              hipStream_t stream) {
    const float* feat  = (const float*)d_in[0];
    const int*   erow  = (const int*)  d_in[1];
    const int*   ecol  = (const int*)  d_in[2];
    const float* eval  = (const float*)d_in[3];
    const float* W0    = (const float*)d_in[4];
    const float* b0    = (const float*)d_in[5];
    const float* W1    = (const float*)d_in[6];
    const float* b1    = (const float*)d_in[7];
    const float* att   = (const float*)d_in[8];
    const float* scale = (const float*)d_in[9];
    const float* offs  = (const float*)d_in[10];
    const int n = in_sizes[0] / DIN;
    const int E = in_sizes[2];

    unsigned short* nsbuf   = (unsigned short*)d_ws;                 // n*128
    unsigned short* h_neigh = nsbuf + (size_t)n * DOUT;              // n*128
    unsigned short* Wbf     = h_neigh + (size_t)n * DOUT;            // 32768
    float* att_self  = (float*)(Wbf + 2 * DOUT * DIN);
    float* att_neigh = att_self  + (size_t)n * NHEAD;
    int*   rowptr    = (int*)(att_neigh + (size_t)n * NHEAD);

    const int nW8 = (2 * DOUT * DIN) / 8;
    kprep<<<(nW8 + n + 1 + 255) / 256, 256, 0, stream>>>(
        W0, W1, erow, (uint4*)Wbf, rowptr, n, E);
    k1_mfma<<<(n + NPB - 1) / NPB, 512, 0, stream>>>(
        feat, (const uint4*)Wbf, b0, b1, att, scale, offs,
        nsbuf, h_neigh, att_self, att_neigh, n);
    k3_agg<<<(n + 15) / 16, 256, 0, stream>>>(rowptr, ecol, eval, att_self, att_neigh,
                                              nsbuf, h_neigh, scale, offs,
                                              (float*)d_out, n);
}